// Round 9
// baseline (144.317 us; speedup 1.0000x reference)
//
#include <hip/hip_runtime.h>

typedef _Float16 half8 __attribute__((ext_vector_type(8)));
typedef _Float16 half2v __attribute__((ext_vector_type(2)));
typedef __fp16   fp16x2 __attribute__((ext_vector_type(2)));
typedef float    f32x4 __attribute__((ext_vector_type(4)));

// Fragment layout (validated R1..R8 end-to-end):
//   value = Wsrc[k][m] at lane l, elem j:  m = mt*16 + (l&15),
//   k = ks*32 + 16*(j>>2) + ((l>>4)<<2) + (j&3)
// ws blob (halfs), COMPACT: L1..L3 frags at (i-1)*16384 + (mt*4+ks)*512 + lane*8
//   W4^T at 49152 + ks*512; W0ext (k=0 -> W0, k=1 -> b0) at 51200 + mt*512
//   total 55296 halfs = 110592 B  (copied linearly into LDS by each block)

__global__ __launch_bounds__(256) void prep_kernel(
    const float* __restrict__ W1, const float* __restrict__ W2,
    const float* __restrict__ W3, const float* __restrict__ W4,
    const float* __restrict__ W0, const float* __restrict__ b0,
    _Float16* __restrict__ out)
{
    int t = blockIdx.x * blockDim.x + threadIdx.x;
    if (t >= 6912) return;
    int lane = t & 63;
    int frag = t >> 6;                 // 0..107
    int col  = lane & 15;
    int kq   = (lane >> 4) << 2;

    if (frag < 96) {
        int l = frag >> 5, f = frag & 31;
        const float* W = (l == 0) ? W1 : (l == 1) ? W2 : W3;
        int mt = f >> 2, ks = f & 3;
        _Float16* dst = out + l * 16384 + f * 512 + lane * 8;
        int m = mt * 16 + col;
        int kbase = ks * 32 + kq;
#pragma unroll
        for (int j = 0; j < 8; ++j) {
            int k = kbase + 16 * (j >> 2) + (j & 3);
            dst[j] = (_Float16)W[k * 128 + m];
        }
    } else if (frag < 100) {
        int ks = frag - 96;
        _Float16* dst = out + 49152 + ks * 512 + lane * 8;
        int m = col;
        int kbase = ks * 32 + kq;
#pragma unroll
        for (int j = 0; j < 8; ++j) {
            int k = kbase + 16 * (j >> 2) + (j & 3);
            float v = (m < 14) ? W4[k * 14 + m] : 0.0f;
            dst[j] = (_Float16)v;
        }
    } else {
        int mt = frag - 100;
        _Float16* dst = out + 51200 + mt * 512 + lane * 8;
        int m = mt * 16 + col;
#pragma unroll
        for (int j = 0; j < 8; ++j) {
            int k = 16 * (j >> 2) + kq + (j & 3);
            float v = (k == 0) ? W0[m] : (k == 1) ? b0[m] : 0.0f;
            dst[j] = (_Float16)v;
        }
    }
}

static __device__ __forceinline__ half2v relu_cvt2(float a, float b) {
    fp16x2 h = __builtin_amdgcn_cvt_pkrtz(a, b);
    fp16x2 zz = {(__fp16)0.0f, (__fp16)0.0f};
    h = __builtin_elementwise_max(h, zz);
    return __builtin_bit_cast(half2v, h);
}

// One hidden 128->128 layer from LDS-resident weights, mt-outer:
// per mt-pair keep only acc[4][2]; each weight frag feeds 4 MFMAs.
static __device__ __forceinline__ void hidden_layer(
    const half8 (&bin)[4][4], half8 (&bout)[4][4],
    const float* __restrict__ bias, const _Float16* Al,
    int lane, int quad)
{
#pragma unroll
    for (int mtp = 0; mtp < 4; ++mtp) {
        f32x4 acc[4][2];
        half8 a[2][4];
#pragma unroll
        for (int h = 0; h < 2; ++h) {
            int mt = 2 * mtp + h;
            f32x4 bv = *(const f32x4*)(bias + mt * 16 + quad * 4);
#pragma unroll
            for (int g = 0; g < 4; ++g) acc[g][h] = bv;
#pragma unroll
            for (int ks = 0; ks < 4; ++ks)
                a[h][ks] = *(const half8*)(Al + (mt * 4 + ks) * 512 + lane * 8);
        }
#pragma unroll
        for (int h = 0; h < 2; ++h)
#pragma unroll
            for (int ks = 0; ks < 4; ++ks)
#pragma unroll
                for (int g = 0; g < 4; ++g)
                    acc[g][h] = __builtin_amdgcn_mfma_f32_16x16x32_f16(a[h][ks], bin[g][ks], acc[g][h], 0, 0, 0);
#pragma unroll
        for (int g = 0; g < 4; ++g) {
            half2v p0 = relu_cvt2(acc[g][0][0], acc[g][0][1]);
            half2v p1 = relu_cvt2(acc[g][0][2], acc[g][0][3]);
            half2v p2 = relu_cvt2(acc[g][1][0], acc[g][1][1]);
            half2v p3 = relu_cvt2(acc[g][1][2], acc[g][1][3]);
            bout[g][mtp][0] = p0[0]; bout[g][mtp][1] = p0[1];
            bout[g][mtp][2] = p1[0]; bout[g][mtp][3] = p1[1];
            bout[g][mtp][4] = p2[0]; bout[g][mtp][5] = p2[1];
            bout[g][mtp][6] = p3[0]; bout[g][mtp][7] = p3[1];
        }
    }
}

// Persistent: 256 blocks (1/CU, LDS-enforced) x 512 threads; weights staged in
// LDS once, then 4 iterations of 512 samples (8 waves x 64 samples).
__global__ __launch_bounds__(512, 2) void nflow_kernel(
    const float* __restrict__ x, const float* __restrict__ z,
    const float* __restrict__ b1, const float* __restrict__ b2,
    const float* __restrict__ b3, const float* __restrict__ b4v,
    const _Float16* __restrict__ Af, float* __restrict__ y, int N)
{
    __shared__ _Float16 wlds[55296];   // 110592 B weight blob
    __shared__ float phis[512][16];    //  32768 B phi staging

    const int tid  = threadIdx.x;
    const int lane = tid & 63;
    const int wid  = tid >> 6;
    const int col  = lane & 15;
    const int quad = lane >> 4;
    const int base0 = blockIdx.x * 2048;

    // ---- one-time weight stage: linear copy ws blob -> LDS (6912 half8s)
    for (int c = tid; c < 6912; c += 512)
        *(half8*)&wlds[c * 8] = *(const half8*)(Af + c * 8);
    __syncthreads();

    for (int it = 0; it < 4; ++it) {
        const int sbase = base0 + it * 512 + wid * 64;
        const int gs    = base0 + it * 512 + tid;
        float zv = (gs < N) ? z[gs] : 0.0f;   // hoisted: hides HBM latency under MFMA

        half8 bufA[4][4], bufB[4][4];

        // ---- layer 0 as MFMA: h0 = relu([x,1]·[W0;b0]) -> bufA
        {
            half8 bx[4];
#pragma unroll
            for (int g = 0; g < 4; ++g) {
                int s = sbase + g * 16 + col;
                float xv = (s < N) ? x[s] : 0.0f;
                half8 t = {};
                if (quad == 0) { t[0] = (_Float16)xv; t[1] = (_Float16)1.0f; }
                bx[g] = t;
            }
#pragma unroll
            for (int mtp = 0; mtp < 4; ++mtp) {
                f32x4 acc[4][2];
                half8 a[2];
#pragma unroll
                for (int h = 0; h < 2; ++h)
                    a[h] = *(const half8*)(&wlds[51200 + (2 * mtp + h) * 512 + lane * 8]);
#pragma unroll
                for (int h = 0; h < 2; ++h)
#pragma unroll
                    for (int g = 0; g < 4; ++g)
                        acc[g][h] = __builtin_amdgcn_mfma_f32_16x16x32_f16(a[h], bx[g], (f32x4){0.f,0.f,0.f,0.f}, 0, 0, 0);
#pragma unroll
                for (int g = 0; g < 4; ++g) {
                    half2v p0 = relu_cvt2(acc[g][0][0], acc[g][0][1]);
                    half2v p1 = relu_cvt2(acc[g][0][2], acc[g][0][3]);
                    half2v p2 = relu_cvt2(acc[g][1][0], acc[g][1][1]);
                    half2v p3 = relu_cvt2(acc[g][1][2], acc[g][1][3]);
                    bufA[g][mtp][0] = p0[0]; bufA[g][mtp][1] = p0[1];
                    bufA[g][mtp][2] = p1[0]; bufA[g][mtp][3] = p1[1];
                    bufA[g][mtp][4] = p2[0]; bufA[g][mtp][5] = p2[1];
                    bufA[g][mtp][6] = p3[0]; bufA[g][mtp][7] = p3[1];
                }
            }
        }

        // ---- hidden layers 1..3 (weights from LDS)
        hidden_layer(bufA, bufB, b1, &wlds[0],     lane, quad);
        hidden_layer(bufB, bufA, b2, &wlds[16384], lane, quad);
        hidden_layer(bufA, bufB, b3, &wlds[32768], lane, quad);

        // ---- layer 4: phi = W4^T·h + b4
        {
            f32x4 acc4[4];
            f32x4 binit;
#pragma unroll
            for (int r = 0; r < 4; ++r) {
                int comp = quad * 4 + r;
                binit[r] = (comp < 14) ? b4v[comp] : 0.0f;
            }
#pragma unroll
            for (int g = 0; g < 4; ++g) acc4[g] = binit;
#pragma unroll
            for (int ks = 0; ks < 4; ++ks) {
                half8 a = *(const half8*)(&wlds[49152 + ks * 512 + lane * 8]);
#pragma unroll
                for (int g = 0; g < 4; ++g)
                    acc4[g] = __builtin_amdgcn_mfma_f32_16x16x32_f16(a, bufB[g][ks], acc4[g], 0, 0, 0);
            }
#pragma unroll
            for (int g = 0; g < 4; ++g)
                *(f32x4*)&phis[wid * 64 + g * 16 + col][quad * 4] = acc4[g];
        }

        __syncthreads();

        // ---- RQS inverse: 512 threads, one sample each
        if (gs < N) {
            float ph[16];
            *(f32x4*)&ph[0]  = *(const f32x4*)&phis[tid][0];
            *(f32x4*)&ph[4]  = *(const f32x4*)&phis[tid][4];
            *(f32x4*)&ph[8]  = *(const f32x4*)&phis[tid][8];
            *(f32x4*)&ph[12] = *(const f32x4*)&phis[tid][12];

            float mw = ph[0], mh = ph[5];
#pragma unroll
            for (int i = 1; i < 5; ++i) { mw = fmaxf(mw, ph[i]); mh = fmaxf(mh, ph[5 + i]); }
            float ew[5], eh[5];
            float sw = 0.f, sh = 0.f;
#pragma unroll
            for (int i = 0; i < 5; ++i) {
                ew[i] = __expf(ph[i] - mw);      sw += ew[i];
                eh[i] = __expf(ph[5 + i] - mh);  sh += eh[i];
            }
            float iw = 10.0f / sw, ih = 10.0f / sh;
            float xk[6], yk[6], dk[6];
            xk[0] = -5.0f; yk[0] = -5.0f;
#pragma unroll
            for (int i = 0; i < 5; ++i) {
                xk[i + 1] = xk[i] + ew[i] * iw;
                yk[i + 1] = yk[i] + eh[i] * ih;
            }
            dk[0] = 1.0f; dk[5] = 1.0f;
#pragma unroll
            for (int i = 0; i < 4; ++i) {
                float v = ph[10 + i];
                dk[i + 1] = 0.0001f + fmaxf(v, 0.0f) + __logf(1.0f + __expf(-fabsf(v)));
            }
            float zc = fminf(fmaxf(zv, -5.0f), 5.0f);
            int k = 0;
#pragma unroll
            for (int i = 1; i <= 4; ++i) k += (zc >= yk[i]) ? 1 : 0;
            float x0 = xk[0], x1 = xk[1], y0 = yk[0], y1 = yk[1], d0 = dk[0], d1 = dk[1];
#pragma unroll
            for (int i = 1; i < 5; ++i)
                if (k == i) { x0 = xk[i]; x1 = xk[i + 1]; y0 = yk[i]; y1 = yk[i + 1]; d0 = dk[i]; d1 = dk[i + 1]; }
            float dx = x1 - x0, dy = y1 - y0;
            float s  = dy / dx;
            float tt = zc - y0;
            float mm = d0 + d1 - 2.0f * s;
            float aa = dy * (s - d0) + tt * mm;
            float bb2 = dy * d0 - tt * mm;
            float cc = -s * tt;
            float disc = fmaxf(bb2 * bb2 - 4.0f * aa * cc, 0.0f);
            float xi   = (2.0f * cc) / (-bb2 - sqrtf(disc));
            float xin  = x0 + xi * dx;
            y[gs] = (fabsf(zv) >= 5.0f) ? zv : xin;
        }

        __syncthreads();   // phis reuse barrier before next iteration
    }
}

extern "C" void kernel_launch(void* const* d_in, const int* in_sizes, int n_in,
                              void* d_out, int out_size, void* d_ws, size_t ws_size,
                              hipStream_t stream) {
    const float* x  = (const float*)d_in[0];
    const float* z  = (const float*)d_in[1];
    const float* W0 = (const float*)d_in[2];
    const float* b0 = (const float*)d_in[3];
    const float* W1 = (const float*)d_in[4];
    const float* b1 = (const float*)d_in[5];
    const float* W2 = (const float*)d_in[6];
    const float* b2 = (const float*)d_in[7];
    const float* W3 = (const float*)d_in[8];
    const float* b3 = (const float*)d_in[9];
    const float* W4 = (const float*)d_in[10];
    const float* b4 = (const float*)d_in[11];
    float* y = (float*)d_out;
    int N = in_sizes[0];

    _Float16* wsH = (_Float16*)d_ws;
    prep_kernel<<<27, 256, 0, stream>>>(W1, W2, W3, W4, W0, b0, wsH);
    nflow_kernel<<<256, 512, 0, stream>>>(x, z, b1, b2, b3, b4, wsH, y, N);
}

// Round 10
// 142.091 us; speedup vs baseline: 1.0157x; 1.0157x over previous
//
#include <hip/hip_runtime.h>

typedef _Float16 half8 __attribute__((ext_vector_type(8)));
typedef _Float16 half2v __attribute__((ext_vector_type(2)));
typedef __fp16   fp16x2 __attribute__((ext_vector_type(2)));
typedef float    f32x4 __attribute__((ext_vector_type(4)));

// Fragment layout (validated R1..R9 end-to-end):
//   value = Wsrc[k][m] at lane l, elem j:  m = mt*16 + (l&15),
//   k = ks*32 + 16*(j>>2) + ((l>>4)<<2) + (j&3)
// ws blob (halfs), COMPACT: L1..L3 frags at (i-1)*16384 + (mt*4+ks)*512 + lane*8
//   W4^T at 49152 + ks*512; W0ext (k=0 -> W0, k=1 -> b0) at 51200 + mt*512

__global__ __launch_bounds__(256) void prep_kernel(
    const float* __restrict__ W1, const float* __restrict__ W2,
    const float* __restrict__ W3, const float* __restrict__ W4,
    const float* __restrict__ W0, const float* __restrict__ b0,
    _Float16* __restrict__ out)
{
    int t = blockIdx.x * blockDim.x + threadIdx.x;
    if (t >= 6912) return;
    int lane = t & 63;
    int frag = t >> 6;                 // 0..107
    int col  = lane & 15;
    int kq   = (lane >> 4) << 2;

    if (frag < 96) {
        int l = frag >> 5, f = frag & 31;
        const float* W = (l == 0) ? W1 : (l == 1) ? W2 : W3;
        int mt = f >> 2, ks = f & 3;
        _Float16* dst = out + l * 16384 + f * 512 + lane * 8;
        int m = mt * 16 + col;
        int kbase = ks * 32 + kq;
#pragma unroll
        for (int j = 0; j < 8; ++j) {
            int k = kbase + 16 * (j >> 2) + (j & 3);
            dst[j] = (_Float16)W[k * 128 + m];
        }
    } else if (frag < 100) {
        int ks = frag - 96;
        _Float16* dst = out + 49152 + ks * 512 + lane * 8;
        int m = col;
        int kbase = ks * 32 + kq;
#pragma unroll
        for (int j = 0; j < 8; ++j) {
            int k = kbase + 16 * (j >> 2) + (j & 3);
            float v = (m < 14) ? W4[k * 14 + m] : 0.0f;
            dst[j] = (_Float16)v;
        }
    } else {
        int mt = frag - 100;
        _Float16* dst = out + 51200 + mt * 512 + lane * 8;
        int m = mt * 16 + col;
#pragma unroll
        for (int j = 0; j < 8; ++j) {
            int k = 16 * (j >> 2) + kq + (j & 3);
            float v = (k == 0) ? W0[m] : (k == 1) ? b0[m] : 0.0f;
            dst[j] = (_Float16)v;
        }
    }
}

static __device__ __forceinline__ half2v relu_cvt2(float a, float b) {
    fp16x2 h = __builtin_amdgcn_cvt_pkrtz(a, b);
    fp16x2 zz = {(__fp16)0.0f, (__fp16)0.0f};
    h = __builtin_elementwise_max(h, zz);
    return __builtin_bit_cast(half2v, h);
}

#define G 6   // sample groups per pair (96 samples/block)

// One hidden 128->128 layer, wave h computing its 4 m-tiles for all G groups.
static __device__ __forceinline__ void hidden_mfma(
    const half8 (&bin)[G][4], half8 (&bNew)[G][2],
    const float* __restrict__ bias, const _Float16* __restrict__ Al,
    int h, int lane, int quad)
{
#pragma unroll
    for (int mtp = 0; mtp < 2; ++mtp) {
        const int mtA = 4 * h + 2 * mtp;
        half8 a[2][4];
#pragma unroll
        for (int hh = 0; hh < 2; ++hh)
#pragma unroll
            for (int ks = 0; ks < 4; ++ks)
                a[hh][ks] = *(const half8*)(Al + ((mtA + hh) * 4 + ks) * 512 + lane * 8);
        f32x4 acc[G][2];
#pragma unroll
        for (int hh = 0; hh < 2; ++hh) {
            f32x4 bv = *(const f32x4*)(bias + (mtA + hh) * 16 + quad * 4);
#pragma unroll
            for (int g = 0; g < G; ++g) acc[g][hh] = bv;
        }
#pragma unroll
        for (int hh = 0; hh < 2; ++hh)
#pragma unroll
            for (int ks = 0; ks < 4; ++ks)
#pragma unroll
                for (int g = 0; g < G; ++g)
                    acc[g][hh] = __builtin_amdgcn_mfma_f32_16x16x32_f16(a[hh][ks], bin[g][ks], acc[g][hh], 0, 0, 0);
#pragma unroll
        for (int g = 0; g < G; ++g)
#pragma unroll
            for (int p = 0; p < 4; ++p) {
                half2v hv = relu_cvt2(acc[g][p >> 1][2 * (p & 1)], acc[g][p >> 1][2 * (p & 1) + 1]);
                bNew[g][mtp][2 * p]     = hv[0];
                bNew[g][mtp][2 * p + 1] = hv[1];
            }
    }
}

// 128-thread block = one wave-pair; 96 samples/block.
__global__ __launch_bounds__(128, 2) void nflow_kernel(
    const float* __restrict__ x, const float* __restrict__ z,
    const float* __restrict__ b1, const float* __restrict__ b2,
    const float* __restrict__ b3, const float* __restrict__ b4v,
    const _Float16* __restrict__ Af, float* __restrict__ y, int N)
{
    __shared__ _Float16 xch[12288];   // 24576 B: [h][g][f] frag slots of 512 halfs
    __shared__ float phis[96][20];    //  7680 B

    const int tid  = threadIdx.x;
    const int lane = tid & 63;
    const int h    = tid >> 6;        // wave half: 0 or 1
    const int col  = lane & 15;
    const int quad = lane >> 4;
    const int base = blockIdx.x * 96;

    const int gsp = base + tid;       // spline sample for tid<96
    float zv = (tid < 96 && gsp < N) ? z[gsp] : 0.0f;   // hoisted load

    half8 bin[G][4];
    half8 bNew[G][2];

#define EXCHANGE()                                                              \
    {                                                                           \
        _Float16* wslot = &xch[(h * G * 2) * 512 + lane * 8];                   \
        const _Float16* rslot = &xch[((1 - h) * G * 2) * 512 + lane * 8];       \
        _Pragma("unroll")                                                       \
        for (int g = 0; g < G; ++g) {                                           \
            *(half8*)&wslot[(g * 2 + 0) * 512] = bNew[g][0];                    \
            *(half8*)&wslot[(g * 2 + 1) * 512] = bNew[g][1];                    \
        }                                                                       \
        __syncthreads();                                                        \
        if (h == 0) {                                                           \
            _Pragma("unroll")                                                   \
            for (int g = 0; g < G; ++g) {                                       \
                bin[g][0] = bNew[g][0];                                         \
                bin[g][1] = bNew[g][1];                                         \
                bin[g][2] = *(const half8*)&rslot[(g * 2 + 0) * 512];           \
                bin[g][3] = *(const half8*)&rslot[(g * 2 + 1) * 512];           \
            }                                                                   \
        } else {                                                                \
            _Pragma("unroll")                                                   \
            for (int g = 0; g < G; ++g) {                                       \
                bin[g][0] = *(const half8*)&rslot[(g * 2 + 0) * 512];           \
                bin[g][1] = *(const half8*)&rslot[(g * 2 + 1) * 512];           \
                bin[g][2] = bNew[g][0];                                         \
                bin[g][3] = bNew[g][1];                                         \
            }                                                                   \
        }                                                                       \
        __syncthreads();                                                        \
    }

    // ---- layer 0: wave h computes its 4 m-tiles of h0 = relu([x,1]·[W0;b0])
    {
        half8 bx[G];
#pragma unroll
        for (int g = 0; g < G; ++g) {
            int s = base + g * 16 + col;
            float xv = (s < N) ? x[s] : 0.0f;
            half8 t = {};
            if (quad == 0) { t[0] = (_Float16)xv; t[1] = (_Float16)1.0f; }
            bx[g] = t;
        }
        half8 a0[4];
#pragma unroll
        for (int mtl = 0; mtl < 4; ++mtl)
            a0[mtl] = *(const half8*)(Af + 51200 + (4 * h + mtl) * 512 + lane * 8);
        f32x4 acc[G][4];
#pragma unroll
        for (int mtl = 0; mtl < 4; ++mtl)
#pragma unroll
            for (int g = 0; g < G; ++g)
                acc[g][mtl] = __builtin_amdgcn_mfma_f32_16x16x32_f16(a0[mtl], bx[g], (f32x4){0.f, 0.f, 0.f, 0.f}, 0, 0, 0);
#pragma unroll
        for (int g = 0; g < G; ++g)
#pragma unroll
            for (int f = 0; f < 2; ++f)
#pragma unroll
                for (int p = 0; p < 4; ++p) {
                    int mtl = 2 * f + (p >> 1), r = 2 * (p & 1);
                    half2v hv = relu_cvt2(acc[g][mtl][r], acc[g][mtl][r + 1]);
                    bNew[g][f][2 * p]     = hv[0];
                    bNew[g][f][2 * p + 1] = hv[1];
                }
    }
    EXCHANGE();

    // ---- hidden layers 1..3
    hidden_mfma(bin, bNew, b1, Af,         h, lane, quad);
    EXCHANGE();
    hidden_mfma(bin, bNew, b2, Af + 16384, h, lane, quad);
    EXCHANGE();
    hidden_mfma(bin, bNew, b3, Af + 32768, h, lane, quad);
    EXCHANGE();

    // ---- layer 4: phi = W4^T·h + b4 ; wave h handles groups 3h..3h+2
    {
        f32x4 binit;
#pragma unroll
        for (int r = 0; r < 4; ++r) {
            int comp = quad * 4 + r;
            binit[r] = (comp < 14) ? b4v[comp] : 0.0f;
        }
        f32x4 acc4[3] = {binit, binit, binit};
        half8 a4[4];
#pragma unroll
        for (int ks = 0; ks < 4; ++ks)
            a4[ks] = *(const half8*)(Af + 49152 + ks * 512 + lane * 8);
        if (h == 0) {
#pragma unroll
            for (int ks = 0; ks < 4; ++ks)
#pragma unroll
                for (int gl = 0; gl < 3; ++gl)
                    acc4[gl] = __builtin_amdgcn_mfma_f32_16x16x32_f16(a4[ks], bin[gl][ks], acc4[gl], 0, 0, 0);
        } else {
#pragma unroll
            for (int ks = 0; ks < 4; ++ks)
#pragma unroll
                for (int gl = 0; gl < 3; ++gl)
                    acc4[gl] = __builtin_amdgcn_mfma_f32_16x16x32_f16(a4[ks], bin[3 + gl][ks], acc4[gl], 0, 0, 0);
        }
#pragma unroll
        for (int gl = 0; gl < 3; ++gl)
            *(f32x4*)&phis[h * 48 + gl * 16 + col][quad * 4] = acc4[gl];
    }
    __syncthreads();

    // ---- RQS inverse: threads 0..95, one sample each
    if (tid < 96 && gsp < N) {
        float ph[16];
        *(f32x4*)&ph[0]  = *(const f32x4*)&phis[tid][0];
        *(f32x4*)&ph[4]  = *(const f32x4*)&phis[tid][4];
        *(f32x4*)&ph[8]  = *(const f32x4*)&phis[tid][8];
        *(f32x4*)&ph[12] = *(const f32x4*)&phis[tid][12];

        float mw = ph[0], mh = ph[5];
#pragma unroll
        for (int i = 1; i < 5; ++i) { mw = fmaxf(mw, ph[i]); mh = fmaxf(mh, ph[5 + i]); }
        float ew[5], eh[5];
        float sw = 0.f, sh = 0.f;
#pragma unroll
        for (int i = 0; i < 5; ++i) {
            ew[i] = __expf(ph[i] - mw);      sw += ew[i];
            eh[i] = __expf(ph[5 + i] - mh);  sh += eh[i];
        }
        float iw = 10.0f / sw, ih = 10.0f / sh;
        float xk[6], yk[6], dk[6];
        xk[0] = -5.0f; yk[0] = -5.0f;
#pragma unroll
        for (int i = 0; i < 5; ++i) {
            xk[i + 1] = xk[i] + ew[i] * iw;
            yk[i + 1] = yk[i] + eh[i] * ih;
        }
        dk[0] = 1.0f; dk[5] = 1.0f;
#pragma unroll
        for (int i = 0; i < 4; ++i) {
            float v = ph[10 + i];
            dk[i + 1] = 0.0001f + fmaxf(v, 0.0f) + __logf(1.0f + __expf(-fabsf(v)));
        }
        float zc = fminf(fmaxf(zv, -5.0f), 5.0f);
        int k = 0;
#pragma unroll
        for (int i = 1; i <= 4; ++i) k += (zc >= yk[i]) ? 1 : 0;
        float x0 = xk[0], x1 = xk[1], y0 = yk[0], y1 = yk[1], d0 = dk[0], d1 = dk[1];
#pragma unroll
        for (int i = 1; i < 5; ++i)
            if (k == i) { x0 = xk[i]; x1 = xk[i + 1]; y0 = yk[i]; y1 = yk[i + 1]; d0 = dk[i]; d1 = dk[i + 1]; }
        float dx = x1 - x0, dy = y1 - y0;
        float s  = dy / dx;
        float tt = zc - y0;
        float mm = d0 + d1 - 2.0f * s;
        float aa = dy * (s - d0) + tt * mm;
        float bb2 = dy * d0 - tt * mm;
        float cc = -s * tt;
        float disc = fmaxf(bb2 * bb2 - 4.0f * aa * cc, 0.0f);
        float xi   = (2.0f * cc) / (-bb2 - sqrtf(disc));
        float xin  = x0 + xi * dx;
        y[gsp] = (fabsf(zv) >= 5.0f) ? zv : xin;
    }
#undef EXCHANGE
}

extern "C" void kernel_launch(void* const* d_in, const int* in_sizes, int n_in,
                              void* d_out, int out_size, void* d_ws, size_t ws_size,
                              hipStream_t stream) {
    const float* x  = (const float*)d_in[0];
    const float* z  = (const float*)d_in[1];
    const float* W0 = (const float*)d_in[2];
    const float* b0 = (const float*)d_in[3];
    const float* W1 = (const float*)d_in[4];
    const float* b1 = (const float*)d_in[5];
    const float* W2 = (const float*)d_in[6];
    const float* b2 = (const float*)d_in[7];
    const float* W3 = (const float*)d_in[8];
    const float* b3 = (const float*)d_in[9];
    const float* W4 = (const float*)d_in[10];
    const float* b4 = (const float*)d_in[11];
    float* y = (float*)d_out;
    int N = in_sizes[0];

    _Float16* wsH = (_Float16*)d_ws;
    prep_kernel<<<27, 256, 0, stream>>>(W1, W2, W3, W4, W0, b0, wsH);
    int nblk = (N + 95) / 96;
    nflow_kernel<<<nblk, 128, 0, stream>>>(x, z, b1, b2, b3, b4, wsH, y, N);
}

// Round 11
// 129.446 us; speedup vs baseline: 1.1149x; 1.0977x over previous
//
#include <hip/hip_runtime.h>

typedef _Float16 half8 __attribute__((ext_vector_type(8)));
typedef _Float16 half2v __attribute__((ext_vector_type(2)));
typedef __fp16   fp16x2 __attribute__((ext_vector_type(2)));
typedef float    f32x4 __attribute__((ext_vector_type(4)));

// Fragment layout (validated R1..R10 end-to-end):
//   value = Wsrc[k][m] at lane l, elem j:  m = mt*16 + (l&15),
//   k = ks*32 + 16*(j>>2) + ((l>>4)<<2) + (j&3)
// ws blob (halfs), COMPACT: L1..L3 frags at (i-1)*16384 + (mt*4+ks)*512 + lane*8
//   W4^T at 49152 + ks*512; W0ext (k=0 -> W0, k=1 -> b0) at 51200 + mt*512

__global__ __launch_bounds__(256) void prep_kernel(
    const float* __restrict__ W1, const float* __restrict__ W2,
    const float* __restrict__ W3, const float* __restrict__ W4,
    const float* __restrict__ W0, const float* __restrict__ b0,
    _Float16* __restrict__ out)
{
    int t = blockIdx.x * blockDim.x + threadIdx.x;
    if (t >= 6912) return;
    int lane = t & 63;
    int frag = t >> 6;                 // 0..107
    int col  = lane & 15;
    int kq   = (lane >> 4) << 2;

    if (frag < 96) {
        int l = frag >> 5, f = frag & 31;
        const float* W = (l == 0) ? W1 : (l == 1) ? W2 : W3;
        int mt = f >> 2, ks = f & 3;
        _Float16* dst = out + l * 16384 + f * 512 + lane * 8;
        int m = mt * 16 + col;
        int kbase = ks * 32 + kq;
#pragma unroll
        for (int j = 0; j < 8; ++j) {
            int k = kbase + 16 * (j >> 2) + (j & 3);
            dst[j] = (_Float16)W[k * 128 + m];
        }
    } else if (frag < 100) {
        int ks = frag - 96;
        _Float16* dst = out + 49152 + ks * 512 + lane * 8;
        int m = col;
        int kbase = ks * 32 + kq;
#pragma unroll
        for (int j = 0; j < 8; ++j) {
            int k = kbase + 16 * (j >> 2) + (j & 3);
            float v = (m < 14) ? W4[k * 14 + m] : 0.0f;
            dst[j] = (_Float16)v;
        }
    } else {
        int mt = frag - 100;
        _Float16* dst = out + 51200 + mt * 512 + lane * 8;
        int m = mt * 16 + col;
#pragma unroll
        for (int j = 0; j < 8; ++j) {
            int k = 16 * (j >> 2) + kq + (j & 3);
            float v = (k == 0) ? W0[m] : (k == 1) ? b0[m] : 0.0f;
            dst[j] = (_Float16)v;
        }
    }
}

static __device__ __forceinline__ half2v relu_cvt2(float a, float b) {
    fp16x2 h = __builtin_amdgcn_cvt_pkrtz(a, b);
    fp16x2 zz = {(__fp16)0.0f, (__fp16)0.0f};
    h = __builtin_elementwise_max(h, zz);
    return __builtin_bit_cast(half2v, h);
}

// Rotating prefetch stage: 8 weight frags + 2 bias vectors for one mt-pair.
struct Stage {
    half8 a[2][4];
    f32x4 bv[2];
};

template<int MTP>
static __device__ __forceinline__ void load_stage(
    Stage& s, const _Float16* __restrict__ Al, const float* __restrict__ bias,
    int lane, int quad)
{
#pragma unroll
    for (int hh = 0; hh < 2; ++hh) {
#pragma unroll
        for (int ks = 0; ks < 4; ++ks)
            s.a[hh][ks] = *(const half8*)(Al + ((2 * MTP + hh) * 4 + ks) * 512 + lane * 8);
        s.bv[hh] = *(const f32x4*)(bias + (2 * MTP + hh) * 16 + quad * 4);
    }
}

// One mt-pair of a hidden layer: 16 MFMA (bias folded in as the C operand of
// the first ks), epilogue packs straight into bout[g][MTP].
template<int MTP>
static __device__ __forceinline__ void mfma_stage(
    const half8 (&bin)[4][4], half8 (&bout)[4][4], const Stage& s)
{
    f32x4 acc[4][2];
#pragma unroll
    for (int hh = 0; hh < 2; ++hh)
#pragma unroll
        for (int g = 0; g < 4; ++g)
            acc[g][hh] = __builtin_amdgcn_mfma_f32_16x16x32_f16(s.a[hh][0], bin[g][0], s.bv[hh], 0, 0, 0);
#pragma unroll
    for (int ks = 1; ks < 4; ++ks)
#pragma unroll
        for (int hh = 0; hh < 2; ++hh)
#pragma unroll
            for (int g = 0; g < 4; ++g)
                acc[g][hh] = __builtin_amdgcn_mfma_f32_16x16x32_f16(s.a[hh][ks], bin[g][ks], acc[g][hh], 0, 0, 0);
#pragma unroll
    for (int g = 0; g < 4; ++g)
#pragma unroll
        for (int p = 0; p < 4; ++p) {
            half2v hv = relu_cvt2(acc[g][p >> 1][2 * (p & 1)], acc[g][p >> 1][2 * (p & 1) + 1]);
            bout[g][MTP][2 * p]     = hv[0];
            bout[g][MTP][2 * p + 1] = hv[1];
        }
}

__global__ __launch_bounds__(256, 2) void nflow_kernel(
    const float* __restrict__ x, const float* __restrict__ z,
    const float* __restrict__ b1, const float* __restrict__ b2,
    const float* __restrict__ b3, const float* __restrict__ b4v,
    const _Float16* __restrict__ Af, float* __restrict__ y, int N)
{
    __shared__ float phis[256][20];   // 20480 B; stride 20 f32 -> conflict-free b128

    const int tid  = threadIdx.x;
    const int lane = tid & 63;
    const int wid  = tid >> 6;
    const int col  = lane & 15;
    const int quad = lane >> 4;
    const int sbase = blockIdx.x * 256 + wid * 64;
    const int gs    = blockIdx.x * 256 + tid;

    float zv = (gs < N) ? z[gs] : 0.0f;   // hoisted ~whole-kernel ahead of use

    const _Float16* A1 = Af;
    const _Float16* A2 = Af + 16384;
    const _Float16* A3 = Af + 32768;

    // ---- L0 weight frags upfront (overlaps x/z load latency)
    half8 aL0[8];
#pragma unroll
    for (int mt = 0; mt < 8; ++mt)
        aL0[mt] = *(const half8*)(Af + 51200 + mt * 512 + lane * 8);

    half8 bx[4];
#pragma unroll
    for (int g = 0; g < 4; ++g) {
        int s = sbase + g * 16 + col;
        float xv = (s < N) ? x[s] : 0.0f;
        half8 t = {};
        if (quad == 0) { t[0] = (_Float16)xv; t[1] = (_Float16)1.0f; }
        bx[g] = t;
    }

    Stage sA, sB;
    load_stage<0>(sA, A1, b1, lane, quad);   // L1 stage-0 prefetch, early

    half8 binA[4][4], binB[4][4];

    // ---- layer 0: h0 = relu([x,1]·[W0;b0]) -> binA
    const f32x4 zero4 = {0.f, 0.f, 0.f, 0.f};
#pragma unroll
    for (int mtp = 0; mtp < 4; ++mtp) {
        f32x4 acc[4][2];
#pragma unroll
        for (int hh = 0; hh < 2; ++hh)
#pragma unroll
            for (int g = 0; g < 4; ++g)
                acc[g][hh] = __builtin_amdgcn_mfma_f32_16x16x32_f16(aL0[2 * mtp + hh], bx[g], zero4, 0, 0, 0);
#pragma unroll
        for (int g = 0; g < 4; ++g)
#pragma unroll
            for (int p = 0; p < 4; ++p) {
                half2v hv = relu_cvt2(acc[g][p >> 1][2 * (p & 1)], acc[g][p >> 1][2 * (p & 1) + 1]);
                binA[g][mtp][2 * p]     = hv[0];
                binA[g][mtp][2 * p + 1] = hv[1];
            }
    }

    // ---- layer 1 (binA -> binB), loads always one stage ahead
    load_stage<1>(sB, A1, b1, lane, quad);
    mfma_stage<0>(binA, binB, sA);
    load_stage<2>(sA, A1, b1, lane, quad);
    mfma_stage<1>(binA, binB, sB);
    load_stage<3>(sB, A1, b1, lane, quad);
    mfma_stage<2>(binA, binB, sA);
    load_stage<0>(sA, A2, b2, lane, quad);   // cross-layer prefetch
    mfma_stage<3>(binA, binB, sB);

    // ---- layer 2 (binB -> binA)
    load_stage<1>(sB, A2, b2, lane, quad);
    mfma_stage<0>(binB, binA, sA);
    load_stage<2>(sA, A2, b2, lane, quad);
    mfma_stage<1>(binB, binA, sB);
    load_stage<3>(sB, A2, b2, lane, quad);
    mfma_stage<2>(binB, binA, sA);
    load_stage<0>(sA, A3, b3, lane, quad);
    mfma_stage<3>(binB, binA, sB);

    // ---- layer 3 (binA -> binB)
    load_stage<1>(sB, A3, b3, lane, quad);
    mfma_stage<0>(binA, binB, sA);
    load_stage<2>(sA, A3, b3, lane, quad);
    mfma_stage<1>(binA, binB, sB);
    load_stage<3>(sB, A3, b3, lane, quad);
    mfma_stage<2>(binA, binB, sA);
    // L4 prefetch during L3's last stage
    half8 a4[4];
#pragma unroll
    for (int ks = 0; ks < 4; ++ks)
        a4[ks] = *(const half8*)(Af + 49152 + ks * 512 + lane * 8);
    f32x4 b4init;
#pragma unroll
    for (int r = 0; r < 4; ++r) {
        int comp = quad * 4 + r;
        b4init[r] = (comp < 14) ? b4v[comp] : 0.0f;
    }
    mfma_stage<3>(binA, binB, sB);

    // ---- layer 4: phi = W4^T·h + b4 (binB -> phis)
    {
        f32x4 acc4[4];
#pragma unroll
        for (int g = 0; g < 4; ++g)
            acc4[g] = __builtin_amdgcn_mfma_f32_16x16x32_f16(a4[0], binB[g][0], b4init, 0, 0, 0);
#pragma unroll
        for (int ks = 1; ks < 4; ++ks)
#pragma unroll
            for (int g = 0; g < 4; ++g)
                acc4[g] = __builtin_amdgcn_mfma_f32_16x16x32_f16(a4[ks], binB[g][ks], acc4[g], 0, 0, 0);
#pragma unroll
        for (int g = 0; g < 4; ++g)
            *(f32x4*)&phis[wid * 64 + g * 16 + col][quad * 4] = acc4[g];
    }

    __syncthreads();

    // ---- RQS inverse: all 256 threads, one sample each
    if (gs < N) {
        float ph[16];
        *(f32x4*)&ph[0]  = *(const f32x4*)&phis[tid][0];
        *(f32x4*)&ph[4]  = *(const f32x4*)&phis[tid][4];
        *(f32x4*)&ph[8]  = *(const f32x4*)&phis[tid][8];
        *(f32x4*)&ph[12] = *(const f32x4*)&phis[tid][12];

        float mw = ph[0], mh = ph[5];
#pragma unroll
        for (int i = 1; i < 5; ++i) { mw = fmaxf(mw, ph[i]); mh = fmaxf(mh, ph[5 + i]); }
        float ew[5], eh[5];
        float sw = 0.f, sh = 0.f;
#pragma unroll
        for (int i = 0; i < 5; ++i) {
            ew[i] = __expf(ph[i] - mw);      sw += ew[i];
            eh[i] = __expf(ph[5 + i] - mh);  sh += eh[i];
        }
        float iw = 10.0f / sw, ih = 10.0f / sh;
        float xk[6], yk[6], dk[6];
        xk[0] = -5.0f; yk[0] = -5.0f;
#pragma unroll
        for (int i = 0; i < 5; ++i) {
            xk[i + 1] = xk[i] + ew[i] * iw;
            yk[i + 1] = yk[i] + eh[i] * ih;
        }
        dk[0] = 1.0f; dk[5] = 1.0f;
#pragma unroll
        for (int i = 0; i < 4; ++i) {
            float v = ph[10 + i];
            dk[i + 1] = 0.0001f + fmaxf(v, 0.0f) + __logf(1.0f + __expf(-fabsf(v)));
        }
        float zc = fminf(fmaxf(zv, -5.0f), 5.0f);
        int k = 0;
#pragma unroll
        for (int i = 1; i <= 4; ++i) k += (zc >= yk[i]) ? 1 : 0;
        float x0 = xk[0], x1 = xk[1], y0 = yk[0], y1 = yk[1], d0 = dk[0], d1 = dk[1];
#pragma unroll
        for (int i = 1; i < 5; ++i)
            if (k == i) { x0 = xk[i]; x1 = xk[i + 1]; y0 = yk[i]; y1 = yk[i + 1]; d0 = dk[i]; d1 = dk[i + 1]; }
        float dx = x1 - x0, dy = y1 - y0;
        float s  = dy / dx;
        float tt = zc - y0;
        float mm = d0 + d1 - 2.0f * s;
        float aa = dy * (s - d0) + tt * mm;
        float bb2 = dy * d0 - tt * mm;
        float cc = -s * tt;
        float disc = fmaxf(bb2 * bb2 - 4.0f * aa * cc, 0.0f);
        float xi   = (2.0f * cc) / (-bb2 - sqrtf(disc));
        float xin  = x0 + xi * dx;
        y[gs] = (fabsf(zv) >= 5.0f) ? zv : xin;
    }
}

extern "C" void kernel_launch(void* const* d_in, const int* in_sizes, int n_in,
                              void* d_out, int out_size, void* d_ws, size_t ws_size,
                              hipStream_t stream) {
    const float* x  = (const float*)d_in[0];
    const float* z  = (const float*)d_in[1];
    const float* W0 = (const float*)d_in[2];
    const float* b0 = (const float*)d_in[3];
    const float* W1 = (const float*)d_in[4];
    const float* b1 = (const float*)d_in[5];
    const float* W2 = (const float*)d_in[6];
    const float* b2 = (const float*)d_in[7];
    const float* W3 = (const float*)d_in[8];
    const float* b3 = (const float*)d_in[9];
    const float* W4 = (const float*)d_in[10];
    const float* b4 = (const float*)d_in[11];
    float* y = (float*)d_out;
    int N = in_sizes[0];

    _Float16* wsH = (_Float16*)d_ws;
    prep_kernel<<<27, 256, 0, stream>>>(W1, W2, W3, W4, W0, b0, wsH);
    int nblk = (N + 255) / 256;
    nflow_kernel<<<nblk, 256, 0, stream>>>(x, z, b1, b2, b3, b4, wsH, y, N);
}

// Round 12
// 122.819 us; speedup vs baseline: 1.1750x; 1.0540x over previous
//
#include <hip/hip_runtime.h>

typedef _Float16 half8 __attribute__((ext_vector_type(8)));
typedef _Float16 half2v __attribute__((ext_vector_type(2)));
typedef __fp16   fp16x2 __attribute__((ext_vector_type(2)));
typedef float    f32x4 __attribute__((ext_vector_type(4)));

// Fragment layout (validated R1..R11 end-to-end):
//   value = Wsrc[k][m] at lane l, elem j:  m = mt*16 + (l&15),
//   k = ks*32 + 16*(j>>2) + ((l>>4)<<2) + (j&3)
// ws blob (halfs), COMPACT: L1..L3 frags at (i-1)*16384 + (mt*4+ks)*512 + lane*8
//   W4^T at 49152 + ks*512; W0ext (k=0 -> W0, k=1 -> b0) at 51200 + mt*512

__global__ __launch_bounds__(256) void prep_kernel(
    const float* __restrict__ W1, const float* __restrict__ W2,
    const float* __restrict__ W3, const float* __restrict__ W4,
    const float* __restrict__ W0, const float* __restrict__ b0,
    _Float16* __restrict__ out)
{
    int t = blockIdx.x * blockDim.x + threadIdx.x;
    if (t >= 6912) return;
    int lane = t & 63;
    int frag = t >> 6;                 // 0..107
    int col  = lane & 15;
    int kq   = (lane >> 4) << 2;

    if (frag < 96) {
        int l = frag >> 5, f = frag & 31;
        const float* W = (l == 0) ? W1 : (l == 1) ? W2 : W3;
        int mt = f >> 2, ks = f & 3;
        _Float16* dst = out + l * 16384 + f * 512 + lane * 8;
        int m = mt * 16 + col;
        int kbase = ks * 32 + kq;
#pragma unroll
        for (int j = 0; j < 8; ++j) {
            int k = kbase + 16 * (j >> 2) + (j & 3);
            dst[j] = (_Float16)W[k * 128 + m];
        }
    } else if (frag < 100) {
        int ks = frag - 96;
        _Float16* dst = out + 49152 + ks * 512 + lane * 8;
        int m = col;
        int kbase = ks * 32 + kq;
#pragma unroll
        for (int j = 0; j < 8; ++j) {
            int k = kbase + 16 * (j >> 2) + (j & 3);
            float v = (m < 14) ? W4[k * 14 + m] : 0.0f;
            dst[j] = (_Float16)v;
        }
    } else {
        int mt = frag - 100;
        _Float16* dst = out + 51200 + mt * 512 + lane * 8;
        int m = mt * 16 + col;
#pragma unroll
        for (int j = 0; j < 8; ++j) {
            int k = 16 * (j >> 2) + kq + (j & 3);
            float v = (k == 0) ? W0[m] : (k == 1) ? b0[m] : 0.0f;
            dst[j] = (_Float16)v;
        }
    }
}

static __device__ __forceinline__ half2v relu_cvt2(float a, float b) {
    fp16x2 h = __builtin_amdgcn_cvt_pkrtz(a, b);
    fp16x2 zz = {(__fp16)0.0f, (__fp16)0.0f};
    h = __builtin_elementwise_max(h, zz);
    return __builtin_bit_cast(half2v, h);
}

// Rotating prefetch stage: 8 weight frags + 2 bias vectors for one mt-pair.
struct Stage {
    half8 a[2][4];
    f32x4 bv[2];
};

template<int MTP>
static __device__ __forceinline__ void load_stage(
    Stage& s, const _Float16* __restrict__ Al, const float* __restrict__ bias,
    int lane, int quad)
{
#pragma unroll
    for (int hh = 0; hh < 2; ++hh) {
#pragma unroll
        for (int ks = 0; ks < 4; ++ks)
            s.a[hh][ks] = *(const half8*)(Al + ((2 * MTP + hh) * 4 + ks) * 512 + lane * 8);
        s.bv[hh] = *(const f32x4*)(bias + (2 * MTP + hh) * 16 + quad * 4);
    }
}

// One mt-pair of a hidden layer: 16 MFMA (bias folded in as the C operand of
// the first ks), epilogue packs straight into bout[g][MTP]. setprio around
// the MFMA cluster (phase-diverse barrier-free waves -> T5 regime).
template<int MTP>
static __device__ __forceinline__ void mfma_stage(
    const half8 (&bin)[4][4], half8 (&bout)[4][4], const Stage& s)
{
    f32x4 acc[4][2];
    __builtin_amdgcn_s_setprio(1);
#pragma unroll
    for (int hh = 0; hh < 2; ++hh)
#pragma unroll
        for (int g = 0; g < 4; ++g)
            acc[g][hh] = __builtin_amdgcn_mfma_f32_16x16x32_f16(s.a[hh][0], bin[g][0], s.bv[hh], 0, 0, 0);
#pragma unroll
    for (int ks = 1; ks < 4; ++ks)
#pragma unroll
        for (int hh = 0; hh < 2; ++hh)
#pragma unroll
            for (int g = 0; g < 4; ++g)
                acc[g][hh] = __builtin_amdgcn_mfma_f32_16x16x32_f16(s.a[hh][ks], bin[g][ks], acc[g][hh], 0, 0, 0);
    __builtin_amdgcn_s_setprio(0);
#pragma unroll
    for (int g = 0; g < 4; ++g)
#pragma unroll
        for (int p = 0; p < 4; ++p) {
            half2v hv = relu_cvt2(acc[g][p >> 1][2 * (p & 1)], acc[g][p >> 1][2 * (p & 1) + 1]);
            bout[g][MTP][2 * p]     = hv[0];
            bout[g][MTP][2 * p + 1] = hv[1];
        }
}

__global__ __launch_bounds__(256, 2) void nflow_kernel(
    const float* __restrict__ x, const float* __restrict__ z,
    const float* __restrict__ b1, const float* __restrict__ b2,
    const float* __restrict__ b3, const float* __restrict__ b4v,
    const _Float16* __restrict__ Af, float* __restrict__ y, int N)
{
    __shared__ float phis[256][20];   // 20480 B; stride 20 f32 -> conflict-free b128

    const int tid  = threadIdx.x;
    const int lane = tid & 63;
    const int wid  = tid >> 6;
    const int col  = lane & 15;
    const int quad = lane >> 4;
    const int sbase = blockIdx.x * 256 + wid * 64;
    const int gs    = blockIdx.x * 256 + tid;

    float zv = (gs < N) ? z[gs] : 0.0f;   // hoisted ~whole-kernel ahead of use

    const _Float16* A1 = Af;
    const _Float16* A2 = Af + 16384;
    const _Float16* A3 = Af + 32768;

    // ---- L0 weight frags upfront (overlaps x/z load latency)
    half8 aL0[8];
#pragma unroll
    for (int mt = 0; mt < 8; ++mt)
        aL0[mt] = *(const half8*)(Af + 51200 + mt * 512 + lane * 8);

    half8 bx[4];
#pragma unroll
    for (int g = 0; g < 4; ++g) {
        int s = sbase + g * 16 + col;
        float xv = (s < N) ? x[s] : 0.0f;
        half8 t = {};
        if (quad == 0) { t[0] = (_Float16)xv; t[1] = (_Float16)1.0f; }
        bx[g] = t;
    }

    Stage sA, sB;
    load_stage<0>(sA, A1, b1, lane, quad);   // L1 stage-0 prefetch, early

    half8 binA[4][4], binB[4][4];

    // ---- layer 0: h0 = relu([x,1]·[W0;b0]) -> binA
    const f32x4 zero4 = {0.f, 0.f, 0.f, 0.f};
    {
        f32x4 acc0[4][8];
        __builtin_amdgcn_s_setprio(1);
#pragma unroll
        for (int mt = 0; mt < 8; ++mt)
#pragma unroll
            for (int g = 0; g < 4; ++g)
                acc0[g][mt] = __builtin_amdgcn_mfma_f32_16x16x32_f16(aL0[mt], bx[g], zero4, 0, 0, 0);
        __builtin_amdgcn_s_setprio(0);
#pragma unroll
        for (int mtp = 0; mtp < 4; ++mtp)
#pragma unroll
            for (int g = 0; g < 4; ++g)
#pragma unroll
                for (int p = 0; p < 4; ++p) {
                    int mt = 2 * mtp + (p >> 1), r = 2 * (p & 1);
                    half2v hv = relu_cvt2(acc0[g][mt][r], acc0[g][mt][r + 1]);
                    binA[g][mtp][2 * p]     = hv[0];
                    binA[g][mtp][2 * p + 1] = hv[1];
                }
    }

    // ---- layer 1 (binA -> binB), loads always one stage ahead
    load_stage<1>(sB, A1, b1, lane, quad);
    mfma_stage<0>(binA, binB, sA);
    load_stage<2>(sA, A1, b1, lane, quad);
    mfma_stage<1>(binA, binB, sB);
    load_stage<3>(sB, A1, b1, lane, quad);
    mfma_stage<2>(binA, binB, sA);
    load_stage<0>(sA, A2, b2, lane, quad);   // cross-layer prefetch
    mfma_stage<3>(binA, binB, sB);

    // ---- layer 2 (binB -> binA)
    load_stage<1>(sB, A2, b2, lane, quad);
    mfma_stage<0>(binB, binA, sA);
    load_stage<2>(sA, A2, b2, lane, quad);
    mfma_stage<1>(binB, binA, sB);
    load_stage<3>(sB, A2, b2, lane, quad);
    mfma_stage<2>(binB, binA, sA);
    load_stage<0>(sA, A3, b3, lane, quad);
    mfma_stage<3>(binB, binA, sB);

    // ---- layer 3 (binA -> binB)
    load_stage<1>(sB, A3, b3, lane, quad);
    mfma_stage<0>(binA, binB, sA);
    load_stage<2>(sA, A3, b3, lane, quad);
    mfma_stage<1>(binA, binB, sB);
    load_stage<3>(sB, A3, b3, lane, quad);
    mfma_stage<2>(binA, binB, sA);
    // L4 prefetch during L3's last stage
    half8 a4[4];
#pragma unroll
    for (int ks = 0; ks < 4; ++ks)
        a4[ks] = *(const half8*)(Af + 49152 + ks * 512 + lane * 8);
    f32x4 b4init;
#pragma unroll
    for (int r = 0; r < 4; ++r) {
        int comp = quad * 4 + r;
        b4init[r] = (comp < 14) ? b4v[comp] : 0.0f;
    }
    mfma_stage<3>(binA, binB, sB);

    // ---- layer 4: phi = W4^T·h + b4 (binB -> phis)
    {
        f32x4 acc4[4];
        __builtin_amdgcn_s_setprio(1);
#pragma unroll
        for (int g = 0; g < 4; ++g)
            acc4[g] = __builtin_amdgcn_mfma_f32_16x16x32_f16(a4[0], binB[g][0], b4init, 0, 0, 0);
#pragma unroll
        for (int ks = 1; ks < 4; ++ks)
#pragma unroll
            for (int g = 0; g < 4; ++g)
                acc4[g] = __builtin_amdgcn_mfma_f32_16x16x32_f16(a4[ks], binB[g][ks], acc4[g], 0, 0, 0);
        __builtin_amdgcn_s_setprio(0);
#pragma unroll
        for (int g = 0; g < 4; ++g)
            *(f32x4*)&phis[wid * 64 + g * 16 + col][quad * 4] = acc4[g];
    }

    // NO __syncthreads: wave wid wrote phis rows [wid*64, wid*64+64) and the
    // spline threads for those rows are the same wave -> intra-wave LDS
    // program order (lgkmcnt) is sufficient. Waves stay fully decoupled.

    // ---- RQS inverse: all 256 threads, one sample each
    if (gs < N) {
        float ph[16];
        *(f32x4*)&ph[0]  = *(const f32x4*)&phis[tid][0];
        *(f32x4*)&ph[4]  = *(const f32x4*)&phis[tid][4];
        *(f32x4*)&ph[8]  = *(const f32x4*)&phis[tid][8];
        *(f32x4*)&ph[12] = *(const f32x4*)&phis[tid][12];

        float mw = ph[0], mh = ph[5];
#pragma unroll
        for (int i = 1; i < 5; ++i) { mw = fmaxf(mw, ph[i]); mh = fmaxf(mh, ph[5 + i]); }
        float ew[5], eh[5];
        float sw = 0.f, sh = 0.f;
#pragma unroll
        for (int i = 0; i < 5; ++i) {
            ew[i] = __expf(ph[i] - mw);      sw += ew[i];
            eh[i] = __expf(ph[5 + i] - mh);  sh += eh[i];
        }
        float iw = 10.0f / sw, ih = 10.0f / sh;
        float xk[6], yk[6], dk[6];
        xk[0] = -5.0f; yk[0] = -5.0f;
#pragma unroll
        for (int i = 0; i < 5; ++i) {
            xk[i + 1] = xk[i] + ew[i] * iw;
            yk[i + 1] = yk[i] + eh[i] * ih;
        }
        dk[0] = 1.0f; dk[5] = 1.0f;
#pragma unroll
        for (int i = 0; i < 4; ++i) {
            float v = ph[10 + i];
            dk[i + 1] = 0.0001f + fmaxf(v, 0.0f) + __logf(1.0f + __expf(-fabsf(v)));
        }
        float zc = fminf(fmaxf(zv, -5.0f), 5.0f);
        int k = 0;
#pragma unroll
        for (int i = 1; i <= 4; ++i) k += (zc >= yk[i]) ? 1 : 0;
        float x0 = xk[0], x1 = xk[1], y0 = yk[0], y1 = yk[1], d0 = dk[0], d1 = dk[1];
#pragma unroll
        for (int i = 1; i < 5; ++i)
            if (k == i) { x0 = xk[i]; x1 = xk[i + 1]; y0 = yk[i]; y1 = yk[i + 1]; d0 = dk[i]; d1 = dk[i + 1]; }
        float dx = x1 - x0, dy = y1 - y0;
        float s  = dy / dx;
        float tt = zc - y0;
        float mm = d0 + d1 - 2.0f * s;
        float aa = dy * (s - d0) + tt * mm;
        float bb2 = dy * d0 - tt * mm;
        float cc = -s * tt;
        float disc = fmaxf(bb2 * bb2 - 4.0f * aa * cc, 0.0f);
        float xi   = (2.0f * cc) / (-bb2 - sqrtf(disc));
        float xin  = x0 + xi * dx;
        y[gs] = (fabsf(zv) >= 5.0f) ? zv : xin;
    }
}

extern "C" void kernel_launch(void* const* d_in, const int* in_sizes, int n_in,
                              void* d_out, int out_size, void* d_ws, size_t ws_size,
                              hipStream_t stream) {
    const float* x  = (const float*)d_in[0];
    const float* z  = (const float*)d_in[1];
    const float* W0 = (const float*)d_in[2];
    const float* b0 = (const float*)d_in[3];
    const float* W1 = (const float*)d_in[4];
    const float* b1 = (const float*)d_in[5];
    const float* W2 = (const float*)d_in[6];
    const float* b2 = (const float*)d_in[7];
    const float* W3 = (const float*)d_in[8];
    const float* b3 = (const float*)d_in[9];
    const float* W4 = (const float*)d_in[10];
    const float* b4 = (const float*)d_in[11];
    float* y = (float*)d_out;
    int N = in_sizes[0];

    _Float16* wsH = (_Float16*)d_ws;
    prep_kernel<<<27, 256, 0, stream>>>(W1, W2, W3, W4, W0, b0, wsH);
    int nblk = (N + 255) / 256;
    nflow_kernel<<<nblk, 256, 0, stream>>>(x, z, b1, b2, b3, b4, wsH, y, N);
}